// Round 3
// baseline (1847.373 us; speedup 1.0000x reference)
//
#include <hip/hip_runtime.h>
#include <hip/hip_bf16.h>
#include <cstddef>
#include <cstdint>

#define N_NODES 20000
#define N_EDGES 100000
#define N_BATCH 512

typedef __attribute__((ext_vector_type(8))) short bf16x8;
typedef __attribute__((ext_vector_type(4))) float f32x4;

__device__ __forceinline__ float sigmoidf_(float x) { return 1.f / (1.f + expf(-x)); }
__device__ __forceinline__ unsigned short f2bf(float x) {
    unsigned int u = __float_as_uint(x);
    unsigned int r = (u + 0x7fffu + ((u >> 16) & 1u)) >> 16;
    return (unsigned short)r;
}
__device__ __forceinline__ float bf2f(unsigned short s) {
    return __uint_as_float(((unsigned int)s) << 16);
}
__device__ __forceinline__ bf16x8 zero8() { bf16x8 z = {0,0,0,0,0,0,0,0}; return z; }

// ---------------- degree (edge count per dst) ----------------
__global__ void deg_kernel(const int* __restrict__ ei, float* __restrict__ deg, int E) {
    int e = blockIdx.x * 256 + threadIdx.x;
    if (e < E) atomicAdd(&deg[ei[E + e]], 1.0f);
}

// ---------------- h = relu(edge_attr @ nn1_w + nn1_b) -> bf16 [E,128] ----------------
__global__ void hidden_kernel(const float* __restrict__ ea, const float* __restrict__ w1,
                              const float* __restrict__ b1, unsigned short* __restrict__ hb) {
    int idx = blockIdx.x * 256 + threadIdx.x;   // e*128 + j
    int e = idx >> 7, j = idx & 127;
    float acc = b1[j];
#pragma unroll
    for (int i = 0; i < 8; i++) acc += ea[e * 8 + i] * w1[i * 128 + j];
    hb[idx] = f2bf(fmaxf(acc, 0.f));
}

// ---------------- pack W2 (+bias slot) into MFMA-B-fragment order ----------------
// Bsw[ks][oc][lane][j] = bf16( W2v[ks*32 + 8*(lane>>4)+j , oc*16 + (lane&15)] )
// W2v[kap, o] = W2flat[kap*64 + o] for kap < 8192; kap in [8192,8256) -> nn2_b
__global__ void bsw_pack(const float* __restrict__ w2, const float* __restrict__ b2,
                         unsigned short* __restrict__ bsw) {
    int idx = blockIdx.x * 256 + threadIdx.x;   // (ks*4+oc)*64 + l ; total 258*4*64=66048
    if (idx >= 66048) return;
    int l = idx & 63, oc = (idx >> 6) & 3, ks = idx >> 8;
    int o = oc * 16 + (l & 15);
    int kap0 = ks * 32 + 8 * (l >> 4);
#pragma unroll
    for (int j = 0; j < 8; ++j) {
        int kap = kap0 + j;            // kap = k*64 + i
        int k = kap >> 6, i = kap & 63;
        float v = (k < 128) ? w2[(size_t)k * 4096 + i * 64 + o] : b2[i * 64 + o];
        bsw[(size_t)idx * 8 + j] = f2bf(v);
    }
}

// ---------------- out = relu(x @ lin0_w + lin0_b) [N,64] ----------------
__global__ void lin0_kernel(const float* __restrict__ x, const float* __restrict__ w,
                            const float* __restrict__ b, float* __restrict__ out) {
    int idx = blockIdx.x * 256 + threadIdx.x;  // n*64 + j
    int n = idx >> 6, j = idx & 63;
    float acc = b[j];
#pragma unroll
    for (int i = 0; i < 16; i++) acc += x[n * 16 + i] * w[i * 64 + j];
    out[idx] = fmaxf(acc, 0.f);
}

// ---------------- fused NNConv message: msg = sum_k h[e,k]*(s_e @ B_k) + s_e @ b2v ----
// 4 waves/block, 64 edges/block, k-split across waves, LDS-atomic reduce.
__global__ __launch_bounds__(256) void msg_mfma(const float* __restrict__ out,
                                                const unsigned short* __restrict__ hb,
                                                const unsigned short* __restrict__ bsw,
                                                const int* __restrict__ ei,
                                                float* __restrict__ agg, int E) {
    __shared__ __align__(16) unsigned short hT[129 * 64];   // reused as float red[4096]
    const int tid = threadIdx.x;
    const int w = tid >> 6, l = tid & 63;
    const int e0 = blockIdx.x * 64;
    const int r16 = l & 15, q = l >> 4;

    // stage hT transposed (cooperative): hT[k][le]; bias slot hT[128][le]=1
    {
        int e = e0 + l;
        bool v = e < E;
        const bf16x8* hrow = (const bf16x8*)(hb + (size_t)e * 128);
#pragma unroll
        for (int cc = 0; cc < 4; ++cc) {
            int c = w * 4 + cc;
            bf16x8 hv = v ? hrow[c] : zero8();
#pragma unroll
            for (int j = 0; j < 8; ++j) hT[(c * 8 + j) * 64 + l] = (unsigned short)hv[j];
        }
        if (w == 0) hT[128 * 64 + l] = v ? (unsigned short)0x3f80 : (unsigned short)0;
    }
    __syncthreads();

    // A fragments: s = out[src[e]] in bf16 (same for all 4 waves)
    bf16x8 sfrag[4][2];
#pragma unroll
    for (int t = 0; t < 4; ++t) {
        int e = e0 + t * 16 + r16;
        int src = (e < E) ? ei[e] : 0;
        const float* srow = out + (size_t)src * 64;
#pragma unroll
        for (int st = 0; st < 2; ++st) {
            bf16x8 f = zero8();
            if (e < E) {
                const float4* p = (const float4*)(srow + st * 32 + q * 8);
                float4 a = p[0], b = p[1];
                f[0] = f2bf(a.x); f[1] = f2bf(a.y); f[2] = f2bf(a.z); f[3] = f2bf(a.w);
                f[4] = f2bf(b.x); f[5] = f2bf(b.y); f[6] = f2bf(b.z); f[7] = f2bf(b.w);
            }
            sfrag[t][st] = f;
        }
    }

    f32x4 acc[4][4] = {};
    const bf16x8* bp = (const bf16x8*)bsw;
    for (int k = w; k < 129; k += 4) {
        bf16x8 bf[2][4];
#pragma unroll
        for (int st = 0; st < 2; ++st)
#pragma unroll
            for (int oc = 0; oc < 4; ++oc)
                bf[st][oc] = bp[((size_t)((k * 2 + st) * 4 + oc) << 6) + l];
#pragma unroll
        for (int t = 0; t < 4; ++t) {
            ushort4 hq = *(const ushort4*)&hT[k * 64 + t * 16 + q * 4];
            float h0 = bf2f(hq.x), h1 = bf2f(hq.y), h2 = bf2f(hq.z), h3 = bf2f(hq.w);
#pragma unroll
            for (int oc = 0; oc < 4; ++oc) {
                f32x4 T = {0.f, 0.f, 0.f, 0.f};
                T = __builtin_amdgcn_mfma_f32_16x16x32_bf16(sfrag[t][0], bf[0][oc], T, 0, 0, 0);
                T = __builtin_amdgcn_mfma_f32_16x16x32_bf16(sfrag[t][1], bf[1][oc], T, 0, 0, 0);
                acc[t][oc][0] += h0 * T[0];
                acc[t][oc][1] += h1 * T[1];
                acc[t][oc][2] += h2 * T[2];
                acc[t][oc][3] += h3 * T[3];
            }
        }
    }
    __syncthreads();

    // zero reduce buffer (reuses hT storage)
    float* red = (float*)hT;
    {
        float4 z = {0.f, 0.f, 0.f, 0.f};
        float4* rp = (float4*)(red + tid * 16);
        rp[0] = z; rp[1] = z; rp[2] = z; rp[3] = z;
    }
    __syncthreads();

    // LDS-atomic accumulate wave partials
#pragma unroll
    for (int t = 0; t < 4; ++t)
#pragma unroll
        for (int oc = 0; oc < 4; ++oc)
#pragma unroll
            for (int r = 0; r < 4; ++r)
                atomicAdd(&red[(t * 16 + q * 4 + r) * 64 + oc * 16 + r16], acc[t][oc][r]);
    __syncthreads();

    // scatter-add reduced rows to agg[dst]
    {
        int el = tid >> 2, o0 = (tid & 3) * 16;
        int e = e0 + el;
        if (e < E) {
            int dst = ei[E + e];
            float* arow = agg + (size_t)dst * 64 + o0;
            const float* rrow = red + el * 64 + o0;
#pragma unroll
            for (int i = 0; i < 16; ++i) atomicAdd(arow + i, rrow[i]);
        }
    }
}

// ---------------- m = relu(agg/deg + out@root_w + root_b); GRU(h=out, m) -> out ------
// also re-zeroes agg for the next message-passing step
__global__ __launch_bounds__(256) void gru_kernel(float* __restrict__ out,
                                                  float* __restrict__ agg,
                                                  const float* __restrict__ deg,
                                                  const float* __restrict__ root_w,
                                                  const float* __restrict__ root_b,
                                                  const float* __restrict__ wih,
                                                  const float* __restrict__ whh,
                                                  const float* __restrict__ bih,
                                                  const float* __restrict__ bhh) {
    int w = threadIdx.x >> 6, j = threadIdx.x & 63;
    int n = blockIdx.x * 4 + w;            // N divisible by 4
    __shared__ float s_o[4][64];
    __shared__ float s_m[4][64];
    s_o[w][j] = out[(size_t)n * 64 + j];
    __syncthreads();
    float d = deg[n]; if (d < 1.f) d = 1.f;
    float mv = agg[(size_t)n * 64 + j] / d + root_b[j];
    agg[(size_t)n * 64 + j] = 0.f;         // re-zero for next step
#pragma unroll 8
    for (int i = 0; i < 64; i++) mv += s_o[w][i] * root_w[i * 64 + j];
    mv = fmaxf(mv, 0.f);
    s_m[w][j] = mv;
    __syncthreads();
    float gi_r = bih[j], gi_z = bih[64 + j], gi_n = bih[128 + j];
    float gh_r = bhh[j], gh_z = bhh[64 + j], gh_n = bhh[128 + j];
#pragma unroll 4
    for (int i = 0; i < 64; i++) {
        float m = s_m[w][i], hv = s_o[w][i];
        gi_r += m * wih[i * 192 + j];
        gi_z += m * wih[i * 192 + 64 + j];
        gi_n += m * wih[i * 192 + 128 + j];
        gh_r += hv * whh[i * 192 + j];
        gh_z += hv * whh[i * 192 + 64 + j];
        gh_n += hv * whh[i * 192 + 128 + j];
    }
    float r = sigmoidf_(gi_r + gh_r);
    float z = sigmoidf_(gi_z + gh_z);
    float nn = tanhf(gi_n + r * gh_n);
    float hnew = (1.f - z) * nn + z * s_o[w][j];
    out[(size_t)n * 64 + j] = hnew;
}

// ---------------- fused Set2Set iteration: LSTM cell + attention pooling ------------
// one block (256 threads) per batch element
__global__ __launch_bounds__(256) void s2s_kernel(const float* __restrict__ out,
                                                  const int* __restrict__ batch,
                                                  float* __restrict__ qstar,
                                                  float* __restrict__ hh, float* __restrict__ cc,
                                                  const float* __restrict__ wih,
                                                  const float* __restrict__ whh,
                                                  const float* __restrict__ bih,
                                                  const float* __restrict__ bhh, int N) {
    int b = blockIdx.x;
    int tid = threadIdx.x;
    int gate = tid >> 6, j = tid & 63;
    __shared__ float s_qs[128];
    __shared__ float s_g[4][64];
    __shared__ float s_q[64];
    __shared__ int s_lo, s_hi;
    __shared__ float s_red[4];
    __shared__ float s_rv[4][64];

    if (tid < 128) s_qs[tid] = qstar[b * 128 + tid];
    if (tid >= 128 && tid < 192) s_q[tid - 128] = hh[b * 64 + (tid - 128)];  // h_prev
    if (tid == 255) {
        int lo = 0, hi = N;
        while (lo < hi) { int mid = (lo + hi) >> 1; if (batch[mid] < b) lo = mid + 1; else hi = mid; }
        s_lo = lo;
        int lo2 = lo, hi2 = N;
        while (lo2 < hi2) { int mid = (lo2 + hi2) >> 1; if (batch[mid] < b + 1) lo2 = mid + 1; else hi2 = mid; }
        s_hi = lo2;
    }
    __syncthreads();

    // LSTM gates (gate g, unit j per thread)
    float g = bih[gate * 64 + j] + bhh[gate * 64 + j];
#pragma unroll 4
    for (int i = 0; i < 128; ++i) g += s_qs[i] * wih[i * 256 + gate * 64 + j];
#pragma unroll 4
    for (int i = 0; i < 64; ++i) g += s_q[i] * whh[i * 256 + gate * 64 + j];
    s_g[gate][j] = g;
    __syncthreads();
    if (gate == 0) {
        float c = sigmoidf_(s_g[1][j]) * cc[b * 64 + j] + sigmoidf_(s_g[0][j]) * tanhf(s_g[2][j]);
        float h = sigmoidf_(s_g[3][j]) * tanhf(c);
        cc[b * 64 + j] = c;
        hh[b * 64 + j] = h;
        qstar[b * 128 + j] = h;
        s_q[j] = h;
    }
    __syncthreads();

    // attention over this graph's node segment
    int lo = s_lo, hi = s_hi;
    int wave = gate, lane = j;
    float wmax = -3.402823e38f;
    for (int n = lo + wave; n < hi; n += 4) {
        float p = out[(size_t)n * 64 + lane] * s_q[lane];
#pragma unroll
        for (int d = 32; d >= 1; d >>= 1) p += __shfl_xor(p, d);
        wmax = fmaxf(wmax, p);
    }
    if (lane == 0) s_red[wave] = wmax;
    __syncthreads();
    float m = fmaxf(fmaxf(s_red[0], s_red[1]), fmaxf(s_red[2], s_red[3]));
    __syncthreads();
    float ssum = 0.f, rv = 0.f;
    for (int n = lo + wave; n < hi; n += 4) {
        float xv = out[(size_t)n * 64 + lane];
        float p = xv * s_q[lane];
#pragma unroll
        for (int d = 32; d >= 1; d >>= 1) p += __shfl_xor(p, d);
        float a = expf(p - m);
        ssum += a;
        rv += a * xv;
    }
    if (lane == 0) s_red[wave] = ssum;
    s_rv[wave][lane] = rv;
    __syncthreads();
    if (wave == 0) {
        float S = s_red[0] + s_red[1] + s_red[2] + s_red[3];
        float r = s_rv[0][lane] + s_rv[1][lane] + s_rv[2][lane] + s_rv[3][lane];
        qstar[b * 128 + 64 + lane] = (S > 0.f) ? r / S : 0.f;
    }
}

// ---------------- head: y = relu(qstar @ lin1 + b1) @ lin2 + b2 ----------------
__global__ __launch_bounds__(256) void final_kernel(const float* __restrict__ qstar,
                                                    const float* __restrict__ w1,
                                                    const float* __restrict__ b1,
                                                    const float* __restrict__ w2,
                                                    const float* __restrict__ b2,
                                                    float* __restrict__ y) {
    int w = threadIdx.x >> 6, j = threadIdx.x & 63;
    int b = blockIdx.x * 4 + w;
    __shared__ float s_qs[4][128];
    s_qs[w][j] = qstar[b * 128 + j];
    s_qs[w][64 + j] = qstar[b * 128 + 64 + j];
    __syncthreads();
    float tv = b1[j];
#pragma unroll 4
    for (int i = 0; i < 128; i++) tv += s_qs[w][i] * w1[i * 64 + j];
    tv = fmaxf(tv, 0.f);
    float p = tv * w2[j];
#pragma unroll
    for (int d = 32; d >= 1; d >>= 1) p += __shfl_xor(p, d);
    if (j == 0) y[b] = p + b2[0];
}

extern "C" void kernel_launch(void* const* d_in, const int* in_sizes, int n_in,
                              void* d_out, int out_size, void* d_ws, size_t ws_size,
                              hipStream_t stream) {
    const int N = N_NODES, E = N_EDGES, B = N_BATCH;
    const float* x       = (const float*)d_in[0];
    const int*   ei      = (const int*)d_in[1];
    const float* ea      = (const float*)d_in[2];
    const int*   batch   = (const int*)d_in[3];
    const float* lin0_w  = (const float*)d_in[4];
    const float* lin0_b  = (const float*)d_in[5];
    const float* nn1_w   = (const float*)d_in[6];
    const float* nn1_b   = (const float*)d_in[7];
    const float* nn2_w   = (const float*)d_in[8];
    const float* nn2_b   = (const float*)d_in[9];
    const float* root_w  = (const float*)d_in[10];
    const float* root_b  = (const float*)d_in[11];
    const float* gru_wih = (const float*)d_in[12];
    const float* gru_whh = (const float*)d_in[13];
    const float* gru_bih = (const float*)d_in[14];
    const float* gru_bhh = (const float*)d_in[15];
    const float* lstm_wih = (const float*)d_in[16];
    const float* lstm_whh = (const float*)d_in[17];
    const float* lstm_bih = (const float*)d_in[18];
    const float* lstm_bhh = (const float*)d_in[19];
    const float* lin1_w  = (const float*)d_in[20];
    const float* lin1_b  = (const float*)d_in[21];
    const float* lin2_w  = (const float*)d_in[22];
    const float* lin2_b  = (const float*)d_in[23];
    float* y = (float*)d_out;

    char* ws = (char*)d_ws;
    size_t off = 0;
    auto alloc = [&](size_t bytes) { void* p = ws + off; off = (off + bytes + 255) & ~(size_t)255; return p; };
    unsigned short* hb  = (unsigned short*)alloc((size_t)E * 128 * 2);   // 25.6 MB
    unsigned short* bsw = (unsigned short*)alloc((size_t)66048 * 8 * 2); // 1.06 MB
    float* out   = (float*)alloc((size_t)N * 64 * 4);                    // 5.12 MB
    float* agg   = (float*)alloc((size_t)N * 64 * 4);                    // 5.12 MB
    float* deg   = (float*)alloc((size_t)N * 4);
    float* qstar = (float*)alloc((size_t)B * 128 * 4);
    float* hh    = (float*)alloc((size_t)B * 64 * 4);
    float* cc    = (float*)alloc((size_t)B * 64 * 4);

    hipMemsetAsync(deg, 0, (size_t)N * 4, stream);
    hipMemsetAsync(agg, 0, (size_t)N * 64 * 4, stream);
    deg_kernel<<<(E + 255) / 256, 256, 0, stream>>>(ei, deg, E);
    hidden_kernel<<<E * 128 / 256, 256, 0, stream>>>(ea, nn1_w, nn1_b, hb);
    bsw_pack<<<258, 256, 0, stream>>>(nn2_w, nn2_b, bsw);
    lin0_kernel<<<N * 64 / 256, 256, 0, stream>>>(x, lin0_w, lin0_b, out);

    for (int step = 0; step < 3; ++step) {
        msg_mfma<<<(E + 63) / 64, 256, 0, stream>>>(out, hb, bsw, ei, agg, E);
        gru_kernel<<<N / 4, 256, 0, stream>>>(out, agg, deg, root_w, root_b,
                                              gru_wih, gru_whh, gru_bih, gru_bhh);
    }

    hipMemsetAsync(qstar, 0, (size_t)B * 128 * 4, stream);
    hipMemsetAsync(hh, 0, (size_t)B * 64 * 4, stream);
    hipMemsetAsync(cc, 0, (size_t)B * 64 * 4, stream);
    for (int tstep = 0; tstep < 3; ++tstep) {
        s2s_kernel<<<B, 256, 0, stream>>>(out, batch, qstar, hh, cc,
                                          lstm_wih, lstm_whh, lstm_bih, lstm_bhh, N);
    }
    final_kernel<<<B / 4, 256, 0, stream>>>(qstar, lin1_w, lin1_b, lin2_w, lin2_b, y);
}

// Round 4
// 886.756 us; speedup vs baseline: 2.0833x; 2.0833x over previous
//
#include <hip/hip_runtime.h>
#include <hip/hip_bf16.h>
#include <cstddef>
#include <cstdint>

#define N_NODES 20000
#define N_EDGES 100000
#define N_BATCH 512

typedef __attribute__((ext_vector_type(8))) short bf16x8;
typedef __attribute__((ext_vector_type(4))) float f32x4;

__device__ __forceinline__ float sigmoidf_(float x) { return 1.f / (1.f + expf(-x)); }
__device__ __forceinline__ unsigned short f2bf(float x) {
    unsigned int u = __float_as_uint(x);
    unsigned int r = (u + 0x7fffu + ((u >> 16) & 1u)) >> 16;
    return (unsigned short)r;
}
__device__ __forceinline__ float bf2f(unsigned short s) {
    return __uint_as_float(((unsigned int)s) << 16);
}
__device__ __forceinline__ bf16x8 zero8() { bf16x8 z = {0,0,0,0,0,0,0,0}; return z; }

// ---------------- degree (edge count per dst) ----------------
__global__ void deg_kernel(const int* __restrict__ ei, float* __restrict__ deg, int E) {
    int e = blockIdx.x * 256 + threadIdx.x;
    if (e < E) atomicAdd(&deg[ei[E + e]], 1.0f);
}

// ---------------- h = relu(edge_attr @ nn1_w + nn1_b) -> bf16 [E,128] ----------------
__global__ void hidden_kernel(const float* __restrict__ ea, const float* __restrict__ w1,
                              const float* __restrict__ b1, unsigned short* __restrict__ hb) {
    int idx = blockIdx.x * 256 + threadIdx.x;   // e*128 + j
    int e = idx >> 7, j = idx & 127;
    float acc = b1[j];
#pragma unroll
    for (int i = 0; i < 8; i++) acc += ea[e * 8 + i] * w1[i * 128 + j];
    hb[idx] = f2bf(fmaxf(acc, 0.f));
}

// ---------------- pack W2 (+bias slot) into MFMA-B-fragment order ----------------
// Bsw[ks][oc][lane][j] = bf16( W2v[ks*32 + 8*(lane>>4)+j , oc*16 + (lane&15)] )
// W2v[kap, o] = W2flat[kap*64 + o] for kap < 8192; kap in [8192,8256) -> nn2_b
__global__ void bsw_pack(const float* __restrict__ w2, const float* __restrict__ b2,
                         unsigned short* __restrict__ bsw) {
    int idx = blockIdx.x * 256 + threadIdx.x;   // (ks*4+oc)*64 + l ; total 258*4*64=66048
    if (idx >= 66048) return;
    int l = idx & 63, oc = (idx >> 6) & 3, ks = idx >> 8;
    int o = oc * 16 + (l & 15);
    int kap0 = ks * 32 + 8 * (l >> 4);
#pragma unroll
    for (int j = 0; j < 8; ++j) {
        int kap = kap0 + j;            // kap = k*64 + i
        int k = kap >> 6, i = kap & 63;
        float v = (k < 128) ? w2[(size_t)k * 4096 + i * 64 + o] : b2[i * 64 + o];
        bsw[(size_t)idx * 8 + j] = f2bf(v);
    }
}

// ---------------- out = relu(x @ lin0_w + lin0_b) [N,64] ----------------
__global__ void lin0_kernel(const float* __restrict__ x, const float* __restrict__ w,
                            const float* __restrict__ b, float* __restrict__ out) {
    int idx = blockIdx.x * 256 + threadIdx.x;  // n*64 + j
    int n = idx >> 6, j = idx & 63;
    float acc = b[j];
#pragma unroll
    for (int i = 0; i < 16; i++) acc += x[n * 16 + i] * w[i * 64 + j];
    out[idx] = fmaxf(acc, 0.f);
}

// ---------------- fused NNConv message: msg = sum_k h[e,k]*(s_e @ B_k) + s_e @ b2v ----
// 4 waves/block, 64 edges/block. k-slots split across waves (k = w, w+4, ...).
// Each wave scatters its own k-partial to agg with coalesced atomics (no reduce).
__global__ __launch_bounds__(256) void msg_mfma(const float* __restrict__ out,
                                                const unsigned short* __restrict__ hb,
                                                const unsigned short* __restrict__ bsw,
                                                const int* __restrict__ ei,
                                                float* __restrict__ agg, int E) {
    __shared__ __align__(16) unsigned short hT[129 * 64];
    const int tid = threadIdx.x;
    const int w = tid >> 6, l = tid & 63;
    const int e0 = blockIdx.x * 64;
    const int r16 = l & 15, q = l >> 4;

    // cooperative hT staging: hT[k][le]; bias slot hT[128][le]=1
    {
        int e = e0 + l;
        bool v = e < E;
        const bf16x8* hrow = (const bf16x8*)(hb + (size_t)e * 128);
#pragma unroll
        for (int cc = 0; cc < 4; ++cc) {
            int c = w * 4 + cc;
            bf16x8 hv = v ? hrow[c] : zero8();
#pragma unroll
            for (int j = 0; j < 8; ++j) hT[(c * 8 + j) * 64 + l] = (unsigned short)hv[j];
        }
        if (w == 0) hT[128 * 64 + l] = v ? (unsigned short)0x3f80 : (unsigned short)0;
    }

    // A fragments: s = out[src[e]] in bf16 (same for all 4 waves; cheap L2-resident reads)
    bf16x8 sfrag[4][2];
#pragma unroll
    for (int t = 0; t < 4; ++t) {
        int e = e0 + t * 16 + r16;
        int src = (e < E) ? ei[e] : 0;
        const float* srow = out + (size_t)src * 64;
#pragma unroll
        for (int st = 0; st < 2; ++st) {
            bf16x8 f = zero8();
            if (e < E) {
                const float4* p = (const float4*)(srow + st * 32 + q * 8);
                float4 a = p[0], b = p[1];
                f[0] = f2bf(a.x); f[1] = f2bf(a.y); f[2] = f2bf(a.z); f[3] = f2bf(a.w);
                f[4] = f2bf(b.x); f[5] = f2bf(b.y); f[6] = f2bf(b.z); f[7] = f2bf(b.w);
            }
            sfrag[t][st] = f;
        }
    }
    __syncthreads();

    f32x4 acc[4][4] = {};
    const bf16x8* bp = (const bf16x8*)bsw;
    for (int k = w; k < 129; k += 4) {
        bf16x8 bf[2][4];
#pragma unroll
        for (int st = 0; st < 2; ++st)
#pragma unroll
            for (int oc = 0; oc < 4; ++oc)
                bf[st][oc] = bp[((k * 8 + st * 4 + oc) << 6) + l];
#pragma unroll
        for (int t = 0; t < 4; ++t) {
            ushort4 hq = *(const ushort4*)&hT[k * 64 + t * 16 + q * 4];
            f32x4 hv;
            hv[0] = bf2f(hq.x); hv[1] = bf2f(hq.y); hv[2] = bf2f(hq.z); hv[3] = bf2f(hq.w);
#pragma unroll
            for (int oc = 0; oc < 4; ++oc) {
                f32x4 T = {0.f, 0.f, 0.f, 0.f};
                T = __builtin_amdgcn_mfma_f32_16x16x32_bf16(sfrag[t][0], bf[0][oc], T, 0, 0, 0);
                T = __builtin_amdgcn_mfma_f32_16x16x32_bf16(sfrag[t][1], bf[1][oc], T, 0, 0, 0);
                acc[t][oc] += hv * T;   // f32x4 -> v_pk_fma_f32 pairs
            }
        }
    }

    // per-wave coalesced scatter of k-partials (R2 pattern: 4 rows x 16 consecutive floats)
#pragma unroll
    for (int t = 0; t < 4; ++t) {
#pragma unroll
        for (int r = 0; r < 4; ++r) {
            int e = e0 + t * 16 + q * 4 + r;
            if (e < E) {
                int dst = ei[E + e];
                float* arow = agg + (size_t)dst * 64 + r16;
#pragma unroll
                for (int oc = 0; oc < 4; ++oc)
                    atomicAdd(arow + oc * 16, acc[t][oc][r]);
            }
        }
    }
}

// ---------------- m = relu(agg/deg + out@root_w + root_b); GRU(h=out, m) -> out ------
// also re-zeroes agg for the next message-passing step
__global__ __launch_bounds__(256) void gru_kernel(float* __restrict__ out,
                                                  float* __restrict__ agg,
                                                  const float* __restrict__ deg,
                                                  const float* __restrict__ root_w,
                                                  const float* __restrict__ root_b,
                                                  const float* __restrict__ wih,
                                                  const float* __restrict__ whh,
                                                  const float* __restrict__ bih,
                                                  const float* __restrict__ bhh) {
    int w = threadIdx.x >> 6, j = threadIdx.x & 63;
    int n = blockIdx.x * 4 + w;            // N divisible by 4
    __shared__ float s_o[4][64];
    __shared__ float s_m[4][64];
    s_o[w][j] = out[(size_t)n * 64 + j];
    __syncthreads();
    float d = deg[n]; if (d < 1.f) d = 1.f;
    float mv = agg[(size_t)n * 64 + j] / d + root_b[j];
    agg[(size_t)n * 64 + j] = 0.f;         // re-zero for next step
#pragma unroll 8
    for (int i = 0; i < 64; i++) mv += s_o[w][i] * root_w[i * 64 + j];
    mv = fmaxf(mv, 0.f);
    s_m[w][j] = mv;
    __syncthreads();
    float gi_r = bih[j], gi_z = bih[64 + j], gi_n = bih[128 + j];
    float gh_r = bhh[j], gh_z = bhh[64 + j], gh_n = bhh[128 + j];
#pragma unroll 4
    for (int i = 0; i < 64; i++) {
        float m = s_m[w][i], hv = s_o[w][i];
        gi_r += m * wih[i * 192 + j];
        gi_z += m * wih[i * 192 + 64 + j];
        gi_n += m * wih[i * 192 + 128 + j];
        gh_r += hv * whh[i * 192 + j];
        gh_z += hv * whh[i * 192 + 64 + j];
        gh_n += hv * whh[i * 192 + 128 + j];
    }
    float r = sigmoidf_(gi_r + gh_r);
    float z = sigmoidf_(gi_z + gh_z);
    float nn = tanhf(gi_n + r * gh_n);
    float hnew = (1.f - z) * nn + z * s_o[w][j];
    out[(size_t)n * 64 + j] = hnew;
}

// ---------------- fused Set2Set iteration: LSTM cell + attention pooling ------------
// one block (256 threads) per batch element
__global__ __launch_bounds__(256) void s2s_kernel(const float* __restrict__ out,
                                                  const int* __restrict__ batch,
                                                  float* __restrict__ qstar,
                                                  float* __restrict__ hh, float* __restrict__ cc,
                                                  const float* __restrict__ wih,
                                                  const float* __restrict__ whh,
                                                  const float* __restrict__ bih,
                                                  const float* __restrict__ bhh, int N) {
    int b = blockIdx.x;
    int tid = threadIdx.x;
    int gate = tid >> 6, j = tid & 63;
    __shared__ float s_qs[128];
    __shared__ float s_g[4][64];
    __shared__ float s_q[64];
    __shared__ int s_lo, s_hi;
    __shared__ float s_red[4];
    __shared__ float s_rv[4][64];

    if (tid < 128) s_qs[tid] = qstar[b * 128 + tid];
    if (tid >= 128 && tid < 192) s_q[tid - 128] = hh[b * 64 + (tid - 128)];  // h_prev
    if (tid == 255) {
        int lo = 0, hi = N;
        while (lo < hi) { int mid = (lo + hi) >> 1; if (batch[mid] < b) lo = mid + 1; else hi = mid; }
        s_lo = lo;
        int lo2 = lo, hi2 = N;
        while (lo2 < hi2) { int mid = (lo2 + hi2) >> 1; if (batch[mid] < b + 1) lo2 = mid + 1; else hi2 = mid; }
        s_hi = lo2;
    }
    __syncthreads();

    // LSTM gates (gate g, unit j per thread)
    float g = bih[gate * 64 + j] + bhh[gate * 64 + j];
#pragma unroll 4
    for (int i = 0; i < 128; ++i) g += s_qs[i] * wih[i * 256 + gate * 64 + j];
#pragma unroll 4
    for (int i = 0; i < 64; ++i) g += s_q[i] * whh[i * 256 + gate * 64 + j];
    s_g[gate][j] = g;
    __syncthreads();
    if (gate == 0) {
        float c = sigmoidf_(s_g[1][j]) * cc[b * 64 + j] + sigmoidf_(s_g[0][j]) * tanhf(s_g[2][j]);
        float h = sigmoidf_(s_g[3][j]) * tanhf(c);
        cc[b * 64 + j] = c;
        hh[b * 64 + j] = h;
        qstar[b * 128 + j] = h;
        s_q[j] = h;
    }
    __syncthreads();

    // attention over this graph's node segment
    int lo = s_lo, hi = s_hi;
    int wave = gate, lane = j;
    float wmax = -3.402823e38f;
    for (int n = lo + wave; n < hi; n += 4) {
        float p = out[(size_t)n * 64 + lane] * s_q[lane];
#pragma unroll
        for (int d = 32; d >= 1; d >>= 1) p += __shfl_xor(p, d);
        wmax = fmaxf(wmax, p);
    }
    if (lane == 0) s_red[wave] = wmax;
    __syncthreads();
    float m = fmaxf(fmaxf(s_red[0], s_red[1]), fmaxf(s_red[2], s_red[3]));
    __syncthreads();
    float ssum = 0.f, rv = 0.f;
    for (int n = lo + wave; n < hi; n += 4) {
        float xv = out[(size_t)n * 64 + lane];
        float p = xv * s_q[lane];
#pragma unroll
        for (int d = 32; d >= 1; d >>= 1) p += __shfl_xor(p, d);
        float a = expf(p - m);
        ssum += a;
        rv += a * xv;
    }
    if (lane == 0) s_red[wave] = ssum;
    s_rv[wave][lane] = rv;
    __syncthreads();
    if (wave == 0) {
        float S = s_red[0] + s_red[1] + s_red[2] + s_red[3];
        float r = s_rv[0][lane] + s_rv[1][lane] + s_rv[2][lane] + s_rv[3][lane];
        qstar[b * 128 + 64 + lane] = (S > 0.f) ? r / S : 0.f;
    }
}

// ---------------- head: y = relu(qstar @ lin1 + b1) @ lin2 + b2 ----------------
__global__ __launch_bounds__(256) void final_kernel(const float* __restrict__ qstar,
                                                    const float* __restrict__ w1,
                                                    const float* __restrict__ b1,
                                                    const float* __restrict__ w2,
                                                    const float* __restrict__ b2,
                                                    float* __restrict__ y) {
    int w = threadIdx.x >> 6, j = threadIdx.x & 63;
    int b = blockIdx.x * 4 + w;
    __shared__ float s_qs[4][128];
    s_qs[w][j] = qstar[b * 128 + j];
    s_qs[w][64 + j] = qstar[b * 128 + 64 + j];
    __syncthreads();
    float tv = b1[j];
#pragma unroll 4
    for (int i = 0; i < 128; i++) tv += s_qs[w][i] * w1[i * 64 + j];
    tv = fmaxf(tv, 0.f);
    float p = tv * w2[j];
#pragma unroll
    for (int d = 32; d >= 1; d >>= 1) p += __shfl_xor(p, d);
    if (j == 0) y[b] = p + b2[0];
}

extern "C" void kernel_launch(void* const* d_in, const int* in_sizes, int n_in,
                              void* d_out, int out_size, void* d_ws, size_t ws_size,
                              hipStream_t stream) {
    const int N = N_NODES, E = N_EDGES, B = N_BATCH;
    const float* x       = (const float*)d_in[0];
    const int*   ei      = (const int*)d_in[1];
    const float* ea      = (const float*)d_in[2];
    const int*   batch   = (const int*)d_in[3];
    const float* lin0_w  = (const float*)d_in[4];
    const float* lin0_b  = (const float*)d_in[5];
    const float* nn1_w   = (const float*)d_in[6];
    const float* nn1_b   = (const float*)d_in[7];
    const float* nn2_w   = (const float*)d_in[8];
    const float* nn2_b   = (const float*)d_in[9];
    const float* root_w  = (const float*)d_in[10];
    const float* root_b  = (const float*)d_in[11];
    const float* gru_wih = (const float*)d_in[12];
    const float* gru_whh = (const float*)d_in[13];
    const float* gru_bih = (const float*)d_in[14];
    const float* gru_bhh = (const float*)d_in[15];
    const float* lstm_wih = (const float*)d_in[16];
    const float* lstm_whh = (const float*)d_in[17];
    const float* lstm_bih = (const float*)d_in[18];
    const float* lstm_bhh = (const float*)d_in[19];
    const float* lin1_w  = (const float*)d_in[20];
    const float* lin1_b  = (const float*)d_in[21];
    const float* lin2_w  = (const float*)d_in[22];
    const float* lin2_b  = (const float*)d_in[23];
    float* y = (float*)d_out;

    char* ws = (char*)d_ws;
    size_t off = 0;
    auto alloc = [&](size_t bytes) { void* p = ws + off; off = (off + bytes + 255) & ~(size_t)255; return p; };
    unsigned short* hb  = (unsigned short*)alloc((size_t)E * 128 * 2);   // 25.6 MB
    unsigned short* bsw = (unsigned short*)alloc((size_t)66048 * 8 * 2); // 1.06 MB
    float* out   = (float*)alloc((size_t)N * 64 * 4);                    // 5.12 MB
    float* agg   = (float*)alloc((size_t)N * 64 * 4);                    // 5.12 MB
    float* deg   = (float*)alloc((size_t)N * 4);
    float* qstar = (float*)alloc((size_t)B * 128 * 4);
    float* hh    = (float*)alloc((size_t)B * 64 * 4);
    float* cc    = (float*)alloc((size_t)B * 64 * 4);

    hipMemsetAsync(deg, 0, (size_t)N * 4, stream);
    hipMemsetAsync(agg, 0, (size_t)N * 64 * 4, stream);
    deg_kernel<<<(E + 255) / 256, 256, 0, stream>>>(ei, deg, E);
    hidden_kernel<<<E * 128 / 256, 256, 0, stream>>>(ea, nn1_w, nn1_b, hb);
    bsw_pack<<<258, 256, 0, stream>>>(nn2_w, nn2_b, bsw);
    lin0_kernel<<<N * 64 / 256, 256, 0, stream>>>(x, lin0_w, lin0_b, out);

    for (int step = 0; step < 3; ++step) {
        msg_mfma<<<(E + 63) / 64, 256, 0, stream>>>(out, hb, bsw, ei, agg, E);
        gru_kernel<<<N / 4, 256, 0, stream>>>(out, agg, deg, root_w, root_b,
                                              gru_wih, gru_whh, gru_bih, gru_bhh);
    }

    hipMemsetAsync(qstar, 0, (size_t)B * 128 * 4, stream);
    hipMemsetAsync(hh, 0, (size_t)B * 64 * 4, stream);
    hipMemsetAsync(cc, 0, (size_t)B * 64 * 4, stream);
    for (int tstep = 0; tstep < 3; ++tstep) {
        s2s_kernel<<<B, 256, 0, stream>>>(out, batch, qstar, hh, cc,
                                          lstm_wih, lstm_whh, lstm_bih, lstm_bhh, N);
    }
    final_kernel<<<B / 4, 256, 0, stream>>>(qstar, lin1_w, lin1_b, lin2_w, lin2_b, y);
}

// Round 5
// 826.205 us; speedup vs baseline: 2.2360x; 1.0733x over previous
//
#include <hip/hip_runtime.h>
#include <hip/hip_bf16.h>
#include <cstddef>
#include <cstdint>

#define N_NODES 20000
#define N_EDGES 100000
#define N_BATCH 512

typedef __attribute__((ext_vector_type(8))) short bf16x8;
typedef __attribute__((ext_vector_type(4))) float f32x4;

__device__ __forceinline__ float sigmoidf_(float x) { return 1.f / (1.f + expf(-x)); }
__device__ __forceinline__ unsigned short f2bf(float x) {
    unsigned int u = __float_as_uint(x);
    unsigned int r = (u + 0x7fffu + ((u >> 16) & 1u)) >> 16;
    return (unsigned short)r;
}
__device__ __forceinline__ float bf2f(unsigned short s) {
    return __uint_as_float(((unsigned int)s) << 16);
}
__device__ __forceinline__ bf16x8 zero8() { bf16x8 z = {0,0,0,0,0,0,0,0}; return z; }

// pack 8 f32 -> bf16x8 via v_cvt_pk_bf16_f32 (RNE), elem j -> VGPR j>>1 half j&1
__device__ __forceinline__ bf16x8 cvt8(f32x4 a, f32x4 b) {
    union { bf16x8 v; unsigned int u[4]; } r;
    asm("v_cvt_pk_bf16_f32 %0, %1, %2" : "=v"(r.u[0]) : "v"(a[0]), "v"(a[1]));
    asm("v_cvt_pk_bf16_f32 %0, %1, %2" : "=v"(r.u[1]) : "v"(a[2]), "v"(a[3]));
    asm("v_cvt_pk_bf16_f32 %0, %1, %2" : "=v"(r.u[2]) : "v"(b[0]), "v"(b[1]));
    asm("v_cvt_pk_bf16_f32 %0, %1, %2" : "=v"(r.u[3]) : "v"(b[2]), "v"(b[3]));
    return r.v;
}

// ============ fused prep: hidden MLP, lin0, bsw pack, degree ============
#define HB_BLOCKS 50000   // E*128/256
#define LIN0_BLOCKS 5000  // N*64/256
#define BSW_BLOCKS 258
#define DEG_BLOCKS 391    // ceil(E/256)

__global__ __launch_bounds__(256) void prep_kernel(
        const float* __restrict__ ea, const float* __restrict__ w1, const float* __restrict__ b1,
        const float* __restrict__ x, const float* __restrict__ l0w, const float* __restrict__ l0b,
        const float* __restrict__ w2, const float* __restrict__ b2,
        const int* __restrict__ ei,
        unsigned short* __restrict__ hb, float* __restrict__ out,
        unsigned short* __restrict__ bsw, float* __restrict__ deg, int E) {
    int bid = blockIdx.x, tid = threadIdx.x;
    if (bid < HB_BLOCKS) {
        int idx = bid * 256 + tid;          // e*128 + j
        int e = idx >> 7, j = idx & 127;
        float acc = b1[j];
#pragma unroll
        for (int i = 0; i < 8; i++) acc += ea[e * 8 + i] * w1[i * 128 + j];
        hb[idx] = f2bf(fmaxf(acc, 0.f));
    } else if (bid < HB_BLOCKS + LIN0_BLOCKS) {
        int idx = (bid - HB_BLOCKS) * 256 + tid;   // n*64 + j
        int n = idx >> 6, j = idx & 63;
        float acc = l0b[j];
#pragma unroll
        for (int i = 0; i < 16; i++) acc += x[n * 16 + i] * l0w[i * 64 + j];
        out[idx] = fmaxf(acc, 0.f);
    } else if (bid < HB_BLOCKS + LIN0_BLOCKS + BSW_BLOCKS) {
        int idx = (bid - HB_BLOCKS - LIN0_BLOCKS) * 256 + tid;
        if (idx < 66048) {
            int l = idx & 63, oc = (idx >> 6) & 3, ks = idx >> 8;
            int o = oc * 16 + (l & 15);
            int kap0 = ks * 32 + 8 * (l >> 4);
#pragma unroll
            for (int j = 0; j < 8; ++j) {
                int kap = kap0 + j;
                int k = kap >> 6, i = kap & 63;
                float v = (k < 128) ? w2[(size_t)k * 4096 + i * 64 + o] : b2[i * 64 + o];
                bsw[(size_t)idx * 8 + j] = f2bf(v);
            }
        }
    } else {
        int e = (bid - HB_BLOCKS - LIN0_BLOCKS - BSW_BLOCKS) * 256 + tid;
        if (e < E) atomicAdd(&deg[ei[E + e]], 1.0f);
    }
}

// ============ fused NNConv message via A-scaled MFMA-C accumulation ============
// msg[e,:] = sum_k (h[e,k]*s_e) @ B_k  + s_e @ b2v   (bias = k==128, h=1)
// 4 waves/block, 64 edges/block, k split across waves, bf double-buffered in regs.
__global__ __launch_bounds__(256) void msg_mfma(const float* __restrict__ out,
                                                const unsigned short* __restrict__ hb,
                                                const unsigned short* __restrict__ bsw,
                                                const int* __restrict__ ei,
                                                float* __restrict__ agg, int E) {
    __shared__ __align__(16) float hs[129 * 64];   // 33 KB, f32
    const int tid = threadIdx.x;
    const int w = tid >> 6, l = tid & 63;
    const int e0 = blockIdx.x * 64;
    const int r16 = l & 15, q = l >> 4;

    // stage hs[k][le] = f32(h[e0+le, k]); bias slot hs[128][le] = 1
    {
        int e = e0 + l;
        bool v = e < E;
        const bf16x8* hrow = (const bf16x8*)(hb + (size_t)e * 128);
#pragma unroll
        for (int cc = 0; cc < 4; ++cc) {
            int c = w * 4 + cc;
            bf16x8 hv = v ? hrow[c] : zero8();
#pragma unroll
            for (int j = 0; j < 8; ++j)
                hs[(c * 8 + j) * 64 + l] = bf2f((unsigned short)hv[j]);
        }
        if (w == 0) hs[128 * 64 + l] = (e < E) ? 1.f : 0.f;
    }

    // A rows in f32: sfp[t][st][h] = out[src[e0+t*16+r16]][st*32+q*8+h*4 ..+4]
    f32x4 sfp[4][2][2];
#pragma unroll
    for (int t = 0; t < 4; ++t) {
        int e = e0 + t * 16 + r16;
        int src = (e < E) ? ei[e] : 0;
        const f32x4* p = (const f32x4*)(out + (size_t)src * 64);
#pragma unroll
        for (int st = 0; st < 2; ++st)
#pragma unroll
            for (int h = 0; h < 2; ++h) {
                f32x4 z = {0.f, 0.f, 0.f, 0.f};
                sfp[t][st][h] = (e < E) ? p[st * 8 + q * 2 + h] : z;
            }
    }

    // first bf buffer (k = w) before barrier to overlap
    const bf16x8* bp = (const bf16x8*)bsw;
    bf16x8 bfA[8], bfB[8];
#pragma unroll
    for (int i = 0; i < 8; ++i) bfA[i] = bp[((w * 8 + i) << 6) + l];

    __syncthreads();

    f32x4 acc[4][4] = {};

#define MSG_COMPUTE(K, BF)                                                     \
    {                                                                          \
        _Pragma("unroll")                                                      \
        for (int t = 0; t < 4; ++t) {                                          \
            float hv = hs[(K) * 64 + t * 16 + r16];                            \
            _Pragma("unroll")                                                  \
            for (int st = 0; st < 2; ++st) {                                   \
                f32x4 p0 = sfp[t][st][0] * hv;                                 \
                f32x4 p1 = sfp[t][st][1] * hv;                                 \
                bf16x8 af = cvt8(p0, p1);                                      \
                _Pragma("unroll")                                              \
                for (int oc = 0; oc < 4; ++oc)                                 \
                    acc[t][oc] = __builtin_amdgcn_mfma_f32_16x16x32_bf16(      \
                        af, BF[st * 4 + oc], acc[t][oc], 0, 0, 0);             \
            }                                                                  \
        }                                                                      \
    }

#pragma unroll 1
    for (int kk = 0; kk < 16; ++kk) {
        int k1 = w + kk * 8;
        int k2 = k1 + 4;
#pragma unroll
        for (int i = 0; i < 8; ++i) bfB[i] = bp[((k2 * 8 + i) << 6) + l];
        MSG_COMPUTE(k1, bfA);
        if (kk < 15) {
            int k3 = k1 + 8;
#pragma unroll
            for (int i = 0; i < 8; ++i) bfA[i] = bp[((k3 * 8 + i) << 6) + l];
        }
        MSG_COMPUTE(k2, bfB);
    }
    // bias pseudo-slot k=128 (h = 1), wave 0 only
    if (w == 0) {
#pragma unroll
        for (int i = 0; i < 8; ++i) bfA[i] = bp[((128 * 8 + i) << 6) + l];
#pragma unroll
        for (int t = 0; t < 4; ++t)
#pragma unroll
            for (int st = 0; st < 2; ++st) {
                bf16x8 af = cvt8(sfp[t][st][0], sfp[t][st][1]);
#pragma unroll
                for (int oc = 0; oc < 4; ++oc)
                    acc[t][oc] = __builtin_amdgcn_mfma_f32_16x16x32_bf16(
                        af, bfA[st * 4 + oc], acc[t][oc], 0, 0, 0);
            }
    }
#undef MSG_COMPUTE

    // coalesced per-wave atomic scatter (R4 pattern: rows x 16 consecutive floats)
#pragma unroll
    for (int t = 0; t < 4; ++t) {
#pragma unroll
        for (int r = 0; r < 4; ++r) {
            int e = e0 + t * 16 + q * 4 + r;
            if (e < E) {
                int dst = ei[E + e];
                float* arow = agg + (size_t)dst * 64 + r16;
#pragma unroll
                for (int oc = 0; oc < 4; ++oc)
                    atomicAdd(arow + oc * 16, acc[t][oc][r]);
            }
        }
    }
}

// ---------------- m = relu(agg/deg + out@root_w + root_b); GRU(h=out, m) -> out ------
__global__ __launch_bounds__(256) void gru_kernel(float* __restrict__ out,
                                                  float* __restrict__ agg,
                                                  const float* __restrict__ deg,
                                                  const float* __restrict__ root_w,
                                                  const float* __restrict__ root_b,
                                                  const float* __restrict__ wih,
                                                  const float* __restrict__ whh,
                                                  const float* __restrict__ bih,
                                                  const float* __restrict__ bhh) {
    int w = threadIdx.x >> 6, j = threadIdx.x & 63;
    int n = blockIdx.x * 4 + w;            // N divisible by 4
    __shared__ float s_o[4][64];
    __shared__ float s_m[4][64];
    s_o[w][j] = out[(size_t)n * 64 + j];
    __syncthreads();
    float d = deg[n]; if (d < 1.f) d = 1.f;
    float mv = agg[(size_t)n * 64 + j] / d + root_b[j];
    agg[(size_t)n * 64 + j] = 0.f;         // re-zero for next step
#pragma unroll 8
    for (int i = 0; i < 64; i++) mv += s_o[w][i] * root_w[i * 64 + j];
    mv = fmaxf(mv, 0.f);
    s_m[w][j] = mv;
    __syncthreads();
    float gi_r = bih[j], gi_z = bih[64 + j], gi_n = bih[128 + j];
    float gh_r = bhh[j], gh_z = bhh[64 + j], gh_n = bhh[128 + j];
#pragma unroll 4
    for (int i = 0; i < 64; i++) {
        float m = s_m[w][i], hv = s_o[w][i];
        gi_r += m * wih[i * 192 + j];
        gi_z += m * wih[i * 192 + 64 + j];
        gi_n += m * wih[i * 192 + 128 + j];
        gh_r += hv * whh[i * 192 + j];
        gh_z += hv * whh[i * 192 + 64 + j];
        gh_n += hv * whh[i * 192 + 128 + j];
    }
    float r = sigmoidf_(gi_r + gh_r);
    float z = sigmoidf_(gi_z + gh_z);
    float nn = tanhf(gi_n + r * gh_n);
    float hnew = (1.f - z) * nn + z * s_o[w][j];
    out[(size_t)n * 64 + j] = hnew;
}

// ============ fused Set2Set (3 iterations) + output head, one block per graph ======
__global__ __launch_bounds__(256) void s2s_final(const float* __restrict__ out,
                                                 const int* __restrict__ batch,
                                                 const float* __restrict__ wih,
                                                 const float* __restrict__ whh,
                                                 const float* __restrict__ bih,
                                                 const float* __restrict__ bhh,
                                                 const float* __restrict__ w1,
                                                 const float* __restrict__ b1,
                                                 const float* __restrict__ w2,
                                                 const float* __restrict__ b2,
                                                 float* __restrict__ y, int N) {
    int b = blockIdx.x;
    int tid = threadIdx.x;
    int gate = tid >> 6, j = tid & 63;
    __shared__ float s_qs[128];
    __shared__ float s_g[4][64];
    __shared__ float s_h[64];
    __shared__ float s_c[64];
    __shared__ int s_lo, s_hi;
    __shared__ float s_red[4];
    __shared__ float s_rv[4][64];

    if (tid < 128) s_qs[tid] = 0.f;
    if (gate == 2) s_h[j] = 0.f;
    if (gate == 3) s_c[j] = 0.f;
    if (tid == 0) {
        int lo = 0, hi = N;
        while (lo < hi) { int mid = (lo + hi) >> 1; if (batch[mid] < b) lo = mid + 1; else hi = mid; }
        s_lo = lo;
        int lo2 = lo, hi2 = N;
        while (lo2 < hi2) { int mid = (lo2 + hi2) >> 1; if (batch[mid] < b + 1) lo2 = mid + 1; else hi2 = mid; }
        s_hi = lo2;
    }
    __syncthreads();

    for (int it = 0; it < 3; ++it) {
        // LSTM gates: thread (gate, j)
        float g = bih[gate * 64 + j] + bhh[gate * 64 + j];
#pragma unroll 4
        for (int i = 0; i < 128; ++i) g += s_qs[i] * wih[i * 256 + gate * 64 + j];
#pragma unroll 4
        for (int i = 0; i < 64; ++i) g += s_h[i] * whh[i * 256 + gate * 64 + j];
        s_g[gate][j] = g;
        __syncthreads();
        if (gate == 0) {
            float c = sigmoidf_(s_g[1][j]) * s_c[j] + sigmoidf_(s_g[0][j]) * tanhf(s_g[2][j]);
            float h = sigmoidf_(s_g[3][j]) * tanhf(c);
            s_c[j] = c;
            s_h[j] = h;
            s_qs[j] = h;   // q part of q_star
        }
        __syncthreads();

        // attention over segment [s_lo, s_hi), q = s_h
        int lo = s_lo, hi = s_hi;
        float wmax = -3.402823e38f;
        for (int n = lo + gate; n < hi; n += 4) {
            float p = out[(size_t)n * 64 + j] * s_h[j];
#pragma unroll
            for (int d = 32; d >= 1; d >>= 1) p += __shfl_xor(p, d);
            wmax = fmaxf(wmax, p);
        }
        if (j == 0) s_red[gate] = wmax;
        __syncthreads();
        float m = fmaxf(fmaxf(s_red[0], s_red[1]), fmaxf(s_red[2], s_red[3]));
        __syncthreads();
        float ssum = 0.f, rv = 0.f;
        for (int n = lo + gate; n < hi; n += 4) {
            float xv = out[(size_t)n * 64 + j];
            float p = xv * s_h[j];
#pragma unroll
            for (int d = 32; d >= 1; d >>= 1) p += __shfl_xor(p, d);
            float a = expf(p - m);
            ssum += a;
            rv += a * xv;
        }
        if (j == 0) s_red[gate] = ssum;
        s_rv[gate][j] = rv;
        __syncthreads();
        if (gate == 0) {
            float S = s_red[0] + s_red[1] + s_red[2] + s_red[3];
            float r = s_rv[0][j] + s_rv[1][j] + s_rv[2][j] + s_rv[3][j];
            s_qs[64 + j] = (S > 0.f) ? r / S : 0.f;
        }
        __syncthreads();
    }

    // head: y = relu(q_star @ w1 + b1) @ w2 + b2
    if (gate == 0) {
        float tv = b1[j];
#pragma unroll 4
        for (int i = 0; i < 128; ++i) tv += s_qs[i] * w1[i * 64 + j];
        tv = fmaxf(tv, 0.f);
        float p = tv * w2[j];
#pragma unroll
        for (int d = 32; d >= 1; d >>= 1) p += __shfl_xor(p, d);
        if (j == 0) y[b] = p + b2[0];
    }
}

extern "C" void kernel_launch(void* const* d_in, const int* in_sizes, int n_in,
                              void* d_out, int out_size, void* d_ws, size_t ws_size,
                              hipStream_t stream) {
    const int N = N_NODES, E = N_EDGES, B = N_BATCH;
    const float* x       = (const float*)d_in[0];
    const int*   ei      = (const int*)d_in[1];
    const float* ea      = (const float*)d_in[2];
    const int*   batch   = (const int*)d_in[3];
    const float* lin0_w  = (const float*)d_in[4];
    const float* lin0_b  = (const float*)d_in[5];
    const float* nn1_w   = (const float*)d_in[6];
    const float* nn1_b   = (const float*)d_in[7];
    const float* nn2_w   = (const float*)d_in[8];
    const float* nn2_b   = (const float*)d_in[9];
    const float* root_w  = (const float*)d_in[10];
    const float* root_b  = (const float*)d_in[11];
    const float* gru_wih = (const float*)d_in[12];
    const float* gru_whh = (const float*)d_in[13];
    const float* gru_bih = (const float*)d_in[14];
    const float* gru_bhh = (const float*)d_in[15];
    const float* lstm_wih = (const float*)d_in[16];
    const float* lstm_whh = (const float*)d_in[17];
    const float* lstm_bih = (const float*)d_in[18];
    const float* lstm_bhh = (const float*)d_in[19];
    const float* lin1_w  = (const float*)d_in[20];
    const float* lin1_b  = (const float*)d_in[21];
    const float* lin2_w  = (const float*)d_in[22];
    const float* lin2_b  = (const float*)d_in[23];
    float* y = (float*)d_out;

    char* ws = (char*)d_ws;
    size_t off = 0;
    auto alloc = [&](size_t bytes) { void* p = ws + off; off = (off + bytes + 255) & ~(size_t)255; return p; };
    unsigned short* hb  = (unsigned short*)alloc((size_t)E * 128 * 2);   // 25.6 MB
    unsigned short* bsw = (unsigned short*)alloc((size_t)66048 * 8 * 2); // 1.06 MB
    float* out   = (float*)alloc((size_t)N * 64 * 4);                    // 5.12 MB
    float* agg   = (float*)alloc((size_t)N * 64 * 4);                    // 5.12 MB
    float* deg   = (float*)alloc((size_t)N * 4);

    hipMemsetAsync(deg, 0, (size_t)N * 4, stream);
    hipMemsetAsync(agg, 0, (size_t)N * 64 * 4, stream);

    prep_kernel<<<HB_BLOCKS + LIN0_BLOCKS + BSW_BLOCKS + DEG_BLOCKS, 256, 0, stream>>>(
        ea, nn1_w, nn1_b, x, lin0_w, lin0_b, nn2_w, nn2_b, ei, hb, out, bsw, deg, E);

    for (int step = 0; step < 3; ++step) {
        msg_mfma<<<(E + 63) / 64, 256, 0, stream>>>(out, hb, bsw, ei, agg, E);
        gru_kernel<<<N / 4, 256, 0, stream>>>(out, agg, deg, root_w, root_b,
                                              gru_wih, gru_whh, gru_bih, gru_bhh);
    }

    s2s_final<<<B, 256, 0, stream>>>(out, batch, lstm_wih, lstm_whh, lstm_bih, lstm_bhh,
                                     lin1_w, lin1_b, lin2_w, lin2_b, y, N);
}

// Round 6
// 823.845 us; speedup vs baseline: 2.2424x; 1.0029x over previous
//
#include <hip/hip_runtime.h>
#include <hip/hip_bf16.h>
#include <hip/hip_fp16.h>
#include <cstddef>
#include <cstdint>

#define N_NODES 20000
#define N_EDGES 100000
#define N_BATCH 512

typedef __attribute__((ext_vector_type(8))) short ushort8_t;
typedef __attribute__((ext_vector_type(8))) _Float16 f16x8;
typedef __attribute__((ext_vector_type(4))) float f32x4;

union F16x8U { f16x8 v; unsigned int u[4]; };

__device__ __forceinline__ float sigmoidf_(float x) { return 1.f / (1.f + expf(-x)); }
__device__ __forceinline__ unsigned short f2h(float x) {
    return __half_as_ushort(__float2half(x));
}

// ============ fused prep: hidden MLP (fp16), lin0, bsw pack (fp16), degree ============
#define HB_BLOCKS 50000   // E*128/256
#define LIN0_BLOCKS 5000  // N*64/256
#define BSW_BLOCKS 258
#define DEG_BLOCKS 391    // ceil(E/256)

__global__ __launch_bounds__(256) void prep_kernel(
        const float* __restrict__ ea, const float* __restrict__ w1, const float* __restrict__ b1,
        const float* __restrict__ x, const float* __restrict__ l0w, const float* __restrict__ l0b,
        const float* __restrict__ w2, const float* __restrict__ b2,
        const int* __restrict__ ei,
        unsigned short* __restrict__ hb, float* __restrict__ out,
        unsigned short* __restrict__ bsw, float* __restrict__ deg, int E) {
    int bid = blockIdx.x, tid = threadIdx.x;
    if (bid < HB_BLOCKS) {
        int idx = bid * 256 + tid;          // e*128 + j
        int e = idx >> 7, j = idx & 127;
        float acc = b1[j];
#pragma unroll
        for (int i = 0; i < 8; i++) acc += ea[e * 8 + i] * w1[i * 128 + j];
        hb[idx] = f2h(fmaxf(acc, 0.f));
    } else if (bid < HB_BLOCKS + LIN0_BLOCKS) {
        int idx = (bid - HB_BLOCKS) * 256 + tid;   // n*64 + j
        int n = idx >> 6, j = idx & 63;
        float acc = l0b[j];
#pragma unroll
        for (int i = 0; i < 16; i++) acc += x[n * 16 + i] * l0w[i * 64 + j];
        out[idx] = fmaxf(acc, 0.f);
    } else if (bid < HB_BLOCKS + LIN0_BLOCKS + BSW_BLOCKS) {
        int idx = (bid - HB_BLOCKS - LIN0_BLOCKS) * 256 + tid;
        if (idx < 66048) {
            int l = idx & 63, oc = (idx >> 6) & 3, ks = idx >> 8;
            int o = oc * 16 + (l & 15);
            int kap0 = ks * 32 + 8 * (l >> 4);
#pragma unroll
            for (int j = 0; j < 8; ++j) {
                int kap = kap0 + j;
                int k = kap >> 6, i = kap & 63;
                float v = (k < 128) ? w2[(size_t)k * 4096 + i * 64 + o] : b2[i * 64 + o];
                bsw[(size_t)idx * 8 + j] = f2h(v);
            }
        }
    } else {
        int e = (bid - HB_BLOCKS - LIN0_BLOCKS - BSW_BLOCKS) * 256 + tid;
        if (e < E) atomicAdd(&deg[ei[E + e]], 1.0f);
    }
}

// ============ fused NNConv message, fp16 MFMA with A = (h_k * s_e) ============
// msg[e,:] = sum_k (h[e,k]*s_e) @ B_k + s_e @ b2v  (bias = pseudo-slot k==128, h=1)
// 4 waves/block, 64 edges/block, k split across waves, B double-buffered in regs.
__global__ __launch_bounds__(256) void msg_mfma(const float* __restrict__ out,
                                                const unsigned short* __restrict__ hb,
                                                const unsigned short* __restrict__ bsw,
                                                const int* __restrict__ ei,
                                                float* __restrict__ agg, int E) {
    __shared__ __align__(16) unsigned int hs[129 * 64];   // (h,h) packed fp16 pairs, 33 KB
    const int tid = threadIdx.x;
    const int w = tid >> 6, l = tid & 63;
    const int e0 = blockIdx.x * 64;
    const int r16 = l & 15, q = l >> 4;

    // stage hs[k][le] = (h,h) fp16 pair; bias slot hs[128][le] = (1,1)
    {
        int e = e0 + l;
        bool v = e < E;
        const ushort8_t* hrow = (const ushort8_t*)(hb + (size_t)e * 128);
#pragma unroll
        for (int cc = 0; cc < 4; ++cc) {
            int c = w * 4 + cc;
            ushort8_t hv = {};
            if (v) hv = hrow[c];
#pragma unroll
            for (int j = 0; j < 8; ++j) {
                unsigned int hu = (unsigned short)hv[j];
                hs[(c * 8 + j) * 64 + l] = (hu << 16) | hu;
            }
        }
        if (w == 0) hs[128 * 64 + l] = v ? 0x3C003C00u : 0u;   // (1.0h, 1.0h)
    }

    // A rows in fp16: sfrag[t][st] = fp16(out[src[e]][st*32 + q*8 .. +8])
    f16x8 sfrag[4][2];
#pragma unroll
    for (int t = 0; t < 4; ++t) {
        int e = e0 + t * 16 + r16;
        int src = (e < E) ? ei[e] : 0;
        const f32x4* p = (const f32x4*)(out + (size_t)src * 64);
#pragma unroll
        for (int st = 0; st < 2; ++st) {
            f16x8 f = {};
            if (e < E) {
                f32x4 a = p[st * 8 + q * 2], b = p[st * 8 + q * 2 + 1];
#pragma unroll
                for (int j = 0; j < 4; ++j) { f[j] = (_Float16)a[j]; f[4 + j] = (_Float16)b[j]; }
            }
            sfrag[t][st] = f;
        }
    }

    // first B buffer (k = w) before barrier to overlap
    const f16x8* bp = (const f16x8*)bsw;
    f16x8 bfA[8], bfB[8];
#pragma unroll
    for (int i = 0; i < 8; ++i) bfA[i] = bp[((w * 8 + i) << 6) + l];

    __syncthreads();

    f32x4 acc[4][4] = {};

#define MSG_COMPUTE(K, BF)                                                     \
    {                                                                          \
        _Pragma("unroll")                                                      \
        for (int t = 0; t < 4; ++t) {                                          \
            unsigned int hh = hs[(K) * 64 + t * 16 + r16];                     \
            _Pragma("unroll")                                                  \
            for (int st = 0; st < 2; ++st) {                                   \
                F16x8U s_, a_;                                                 \
                s_.v = sfrag[t][st];                                           \
                asm("v_pk_mul_f16 %0, %1, %2" : "=v"(a_.u[0]) : "v"(hh), "v"(s_.u[0])); \
                asm("v_pk_mul_f16 %0, %1, %2" : "=v"(a_.u[1]) : "v"(hh), "v"(s_.u[1])); \
                asm("v_pk_mul_f16 %0, %1, %2" : "=v"(a_.u[2]) : "v"(hh), "v"(s_.u[2])); \
                asm("v_pk_mul_f16 %0, %1, %2" : "=v"(a_.u[3]) : "v"(hh), "v"(s_.u[3])); \
                _Pragma("unroll")                                              \
                for (int oc = 0; oc < 4; ++oc)                                 \
                    acc[t][oc] = __builtin_amdgcn_mfma_f32_16x16x32_f16(       \
                        a_.v, BF[st * 4 + oc], acc[t][oc], 0, 0, 0);           \
            }                                                                  \
        }                                                                      \
    }

#pragma unroll 1
    for (int kk = 0; kk < 16; ++kk) {
        int k1 = w + kk * 8;
        int k2 = k1 + 4;
#pragma unroll
        for (int i = 0; i < 8; ++i) bfB[i] = bp[((k2 * 8 + i) << 6) + l];
        MSG_COMPUTE(k1, bfA);
        if (kk < 15) {
            int k3 = k1 + 8;
#pragma unroll
            for (int i = 0; i < 8; ++i) bfA[i] = bp[((k3 * 8 + i) << 6) + l];
        }
        MSG_COMPUTE(k2, bfB);
    }
#undef MSG_COMPUTE

    // bias pseudo-slot k=128 (h = 1): af = sfrag directly, wave 0 only
    if (w == 0) {
#pragma unroll
        for (int i = 0; i < 8; ++i) bfA[i] = bp[((128 * 8 + i) << 6) + l];
#pragma unroll
        for (int t = 0; t < 4; ++t)
#pragma unroll
            for (int st = 0; st < 2; ++st)
#pragma unroll
                for (int oc = 0; oc < 4; ++oc)
                    acc[t][oc] = __builtin_amdgcn_mfma_f32_16x16x32_f16(
                        sfrag[t][st], bfA[st * 4 + oc], acc[t][oc], 0, 0, 0);
    }

    // coalesced per-wave atomic scatter (rows x 16 consecutive floats)
#pragma unroll
    for (int t = 0; t < 4; ++t) {
#pragma unroll
        for (int r = 0; r < 4; ++r) {
            int e = e0 + t * 16 + q * 4 + r;
            if (e < E) {
                int dst = ei[E + e];
                float* arow = agg + (size_t)dst * 64 + r16;
#pragma unroll
                for (int oc = 0; oc < 4; ++oc)
                    atomicAdd(arow + oc * 16, acc[t][oc][r]);
            }
        }
    }
}

// ---------------- m = relu(agg/deg + out@root_w + root_b); GRU(h=out, m) -> out ------
__global__ __launch_bounds__(256) void gru_kernel(float* __restrict__ out,
                                                  float* __restrict__ agg,
                                                  const float* __restrict__ deg,
                                                  const float* __restrict__ root_w,
                                                  const float* __restrict__ root_b,
                                                  const float* __restrict__ wih,
                                                  const float* __restrict__ whh,
                                                  const float* __restrict__ bih,
                                                  const float* __restrict__ bhh) {
    int w = threadIdx.x >> 6, j = threadIdx.x & 63;
    int n = blockIdx.x * 4 + w;            // N divisible by 4
    __shared__ float s_o[4][64];
    __shared__ float s_m[4][64];
    s_o[w][j] = out[(size_t)n * 64 + j];
    __syncthreads();
    float d = deg[n]; if (d < 1.f) d = 1.f;
    float mv = agg[(size_t)n * 64 + j] / d + root_b[j];
    agg[(size_t)n * 64 + j] = 0.f;         // re-zero for next step
#pragma unroll 8
    for (int i = 0; i < 64; i++) mv += s_o[w][i] * root_w[i * 64 + j];
    mv = fmaxf(mv, 0.f);
    s_m[w][j] = mv;
    __syncthreads();
    float gi_r = bih[j], gi_z = bih[64 + j], gi_n = bih[128 + j];
    float gh_r = bhh[j], gh_z = bhh[64 + j], gh_n = bhh[128 + j];
#pragma unroll 4
    for (int i = 0; i < 64; i++) {
        float m = s_m[w][i], hv = s_o[w][i];
        gi_r += m * wih[i * 192 + j];
        gi_z += m * wih[i * 192 + 64 + j];
        gi_n += m * wih[i * 192 + 128 + j];
        gh_r += hv * whh[i * 192 + j];
        gh_z += hv * whh[i * 192 + 64 + j];
        gh_n += hv * whh[i * 192 + 128 + j];
    }
    float r = sigmoidf_(gi_r + gh_r);
    float z = sigmoidf_(gi_z + gh_z);
    float nn = tanhf(gi_n + r * gh_n);
    float hnew = (1.f - z) * nn + z * s_o[w][j];
    out[(size_t)n * 64 + j] = hnew;
}

// ============ fused Set2Set (3 iterations) + output head, one block per graph ======
__global__ __launch_bounds__(256) void s2s_final(const float* __restrict__ out,
                                                 const int* __restrict__ batch,
                                                 const float* __restrict__ wih,
                                                 const float* __restrict__ whh,
                                                 const float* __restrict__ bih,
                                                 const float* __restrict__ bhh,
                                                 const float* __restrict__ w1,
                                                 const float* __restrict__ b1,
                                                 const float* __restrict__ w2,
                                                 const float* __restrict__ b2,
                                                 float* __restrict__ y, int N) {
    int b = blockIdx.x;
    int tid = threadIdx.x;
    int gate = tid >> 6, j = tid & 63;
    __shared__ float s_qs[128];
    __shared__ float s_g[4][64];
    __shared__ float s_h[64];
    __shared__ float s_c[64];
    __shared__ int s_lo, s_hi;
    __shared__ float s_red[4];
    __shared__ float s_rv[4][64];

    if (tid < 128) s_qs[tid] = 0.f;
    if (gate == 2) s_h[j] = 0.f;
    if (gate == 3) s_c[j] = 0.f;
    if (tid == 0) {
        int lo = 0, hi = N;
        while (lo < hi) { int mid = (lo + hi) >> 1; if (batch[mid] < b) lo = mid + 1; else hi = mid; }
        s_lo = lo;
        int lo2 = lo, hi2 = N;
        while (lo2 < hi2) { int mid = (lo2 + hi2) >> 1; if (batch[mid] < b + 1) lo2 = mid + 1; else hi2 = mid; }
        s_hi = lo2;
    }
    __syncthreads();

    for (int it = 0; it < 3; ++it) {
        float g = bih[gate * 64 + j] + bhh[gate * 64 + j];
#pragma unroll 4
        for (int i = 0; i < 128; ++i) g += s_qs[i] * wih[i * 256 + gate * 64 + j];
#pragma unroll 4
        for (int i = 0; i < 64; ++i) g += s_h[i] * whh[i * 256 + gate * 64 + j];
        s_g[gate][j] = g;
        __syncthreads();
        if (gate == 0) {
            float c = sigmoidf_(s_g[1][j]) * s_c[j] + sigmoidf_(s_g[0][j]) * tanhf(s_g[2][j]);
            float h = sigmoidf_(s_g[3][j]) * tanhf(c);
            s_c[j] = c;
            s_h[j] = h;
            s_qs[j] = h;
        }
        __syncthreads();

        int lo = s_lo, hi = s_hi;
        float wmax = -3.402823e38f;
        for (int n = lo + gate; n < hi; n += 4) {
            float p = out[(size_t)n * 64 + j] * s_h[j];
#pragma unroll
            for (int d = 32; d >= 1; d >>= 1) p += __shfl_xor(p, d);
            wmax = fmaxf(wmax, p);
        }
        if (j == 0) s_red[gate] = wmax;
        __syncthreads();
        float m = fmaxf(fmaxf(s_red[0], s_red[1]), fmaxf(s_red[2], s_red[3]));
        __syncthreads();
        float ssum = 0.f, rv = 0.f;
        for (int n = lo + gate; n < hi; n += 4) {
            float xv = out[(size_t)n * 64 + j];
            float p = xv * s_h[j];
#pragma unroll
            for (int d = 32; d >= 1; d >>= 1) p += __shfl_xor(p, d);
            float a = expf(p - m);
            ssum += a;
            rv += a * xv;
        }
        if (j == 0) s_red[gate] = ssum;
        s_rv[gate][j] = rv;
        __syncthreads();
        if (gate == 0) {
            float S = s_red[0] + s_red[1] + s_red[2] + s_red[3];
            float r = s_rv[0][j] + s_rv[1][j] + s_rv[2][j] + s_rv[3][j];
            s_qs[64 + j] = (S > 0.f) ? r / S : 0.f;
        }
        __syncthreads();
    }

    if (gate == 0) {
        float tv = b1[j];
#pragma unroll 4
        for (int i = 0; i < 128; ++i) tv += s_qs[i] * w1[i * 64 + j];
        tv = fmaxf(tv, 0.f);
        float p = tv * w2[j];
#pragma unroll
        for (int d = 32; d >= 1; d >>= 1) p += __shfl_xor(p, d);
        if (j == 0) y[b] = p + b2[0];
    }
}

extern "C" void kernel_launch(void* const* d_in, const int* in_sizes, int n_in,
                              void* d_out, int out_size, void* d_ws, size_t ws_size,
                              hipStream_t stream) {
    const int N = N_NODES, E = N_EDGES, B = N_BATCH;
    const float* x       = (const float*)d_in[0];
    const int*   ei      = (const int*)d_in[1];
    const float* ea      = (const float*)d_in[2];
    const int*   batch   = (const int*)d_in[3];
    const float* lin0_w  = (const float*)d_in[4];
    const float* lin0_b  = (const float*)d_in[5];
    const float* nn1_w   = (const float*)d_in[6];
    const float* nn1_b   = (const float*)d_in[7];
    const float* nn2_w   = (const float*)d_in[8];
    const float* nn2_b   = (const float*)d_in[9];
    const float* root_w  = (const float*)d_in[10];
    const float* root_b  = (const float*)d_in[11];
    const float* gru_wih = (const float*)d_in[12];
    const float* gru_whh = (const float*)d_in[13];
    const float* gru_bih = (const float*)d_in[14];
    const float* gru_bhh = (const float*)d_in[15];
    const float* lstm_wih = (const float*)d_in[16];
    const float* lstm_whh = (const float*)d_in[17];
    const float* lstm_bih = (const float*)d_in[18];
    const float* lstm_bhh = (const float*)d_in[19];
    const float* lin1_w  = (const float*)d_in[20];
    const float* lin1_b  = (const float*)d_in[21];
    const float* lin2_w  = (const float*)d_in[22];
    const float* lin2_b  = (const float*)d_in[23];
    float* y = (float*)d_out;

    char* ws = (char*)d_ws;
    size_t off = 0;
    auto alloc = [&](size_t bytes) { void* p = ws + off; off = (off + bytes + 255) & ~(size_t)255; return p; };
    unsigned short* hb  = (unsigned short*)alloc((size_t)E * 128 * 2);   // 25.6 MB fp16
    unsigned short* bsw = (unsigned short*)alloc((size_t)66048 * 8 * 2); // 1.06 MB fp16
    float* out   = (float*)alloc((size_t)N * 64 * 4);                    // 5.12 MB
    float* agg   = (float*)alloc((size_t)N * 64 * 4);                    // 5.12 MB
    float* deg   = (float*)alloc((size_t)N * 4);

    hipMemsetAsync(deg, 0, (size_t)N * 4, stream);
    hipMemsetAsync(agg, 0, (size_t)N * 64 * 4, stream);

    prep_kernel<<<HB_BLOCKS + LIN0_BLOCKS + BSW_BLOCKS + DEG_BLOCKS, 256, 0, stream>>>(
        ea, nn1_w, nn1_b, x, lin0_w, lin0_b, nn2_w, nn2_b, ei, hb, out, bsw, deg, E);

    for (int step = 0; step < 3; ++step) {
        msg_mfma<<<(E + 63) / 64, 256, 0, stream>>>(out, hb, bsw, ei, agg, E);
        gru_kernel<<<N / 4, 256, 0, stream>>>(out, agg, deg, root_w, root_b,
                                              gru_wih, gru_whh, gru_bih, gru_bhh);
    }

    s2s_final<<<B, 256, 0, stream>>>(out, batch, lstm_wih, lstm_whh, lstm_bih, lstm_bhh,
                                     lin1_w, lin1_b, lin2_w, lin2_b, y, N);
}